// Round 15
// baseline (51.368 us; speedup 1.0000x reference)
//
#include <hip/hip_runtime.h>
#include <hip/hip_bf16.h>
#include <math.h>

namespace {
constexpr int Bn = 8;
constexpr int Ln = 8192;
constexpr int Rn = 64;
constexpr int Hn = 512;
constexpr int LT = 128;
constexpr int NSEG = Ln / LT;            // 64 segments per batch
constexpr int NK1 = Bn * NSEG;           // 512 k1 blocks
constexpr int NHC = 4;                   // M h-chunks (128 h each)

// workspace float offsets
// per-k1-block partial: A1 bf16[4096] (2048 f), A2 bf16[4096] (2048 f),
//                       u1 f32[64], u2 f32[64], sig f32[2], pad
constexpr size_t PS        = 4352;
constexpr size_t OFF_G     = 0;                                   // fp32 G 64x64
constexpr size_t OFF_W     = 4096;                                // 64
constexpr size_t OFF_BB    = 4160;                                // 1 (+pad)
constexpr size_t OFF_STATS = 4224;                                // NK1 * PS
constexpr size_t OFF_A1R   = OFF_STATS + (size_t)NK1 * PS;        // B*4096
constexpr size_t OFF_A2R   = OFF_A1R + (size_t)Bn * 4096;         // B*4096
constexpr size_t OFF_U1R   = OFF_A2R + (size_t)Bn * 4096;         // B*64
constexpr size_t OFF_U2R   = OFF_U1R + (size_t)Bn * 64;           // B*64
constexpr size_t OFF_SIG   = OFF_U2R + (size_t)Bn * 64;           // B*2 (pad 64)
constexpr size_t OFF_MP    = OFF_SIG + 64;                        // B*NHC*64*H (M h-partials)
constexpr size_t OFF_C1P   = OFF_MP + (size_t)Bn * NHC * 64 * Hn; // B*NHC*H
constexpr size_t OFF_TD    = OFF_C1P + (size_t)Bn * NHC * Hn;     // B*64*H
constexpr size_t OFF_P1    = OFF_TD + (size_t)Bn * 64 * Hn;       // B*H
constexpr size_t OFF_P2    = OFF_P1 + (size_t)Bn * Hn;            // B*H
constexpr size_t OFF_Q1    = OFF_P2 + (size_t)Bn * Hn;            // B*H
constexpr size_t OFF_GV    = OFF_Q1 + (size_t)Bn * Hn;            // B*H (g = u2^T M)
}

using short8v = __attribute__((ext_vector_type(8))) short;
using f32x4v  = __attribute__((ext_vector_type(4))) float;

// bf16 [64 r][128 l], 8-elem granules XOR-swizzled by row (HW-validated R8/R9)
__device__ __forceinline__ int bidx(int r, int l) {
  return (r << 7) + ((((l >> 3) ^ (r & 7)) << 3) | (l & 7));
}
// bf16 [128 l][64 r]
__device__ __forceinline__ int xlidx(int l, int r) {
  return (l << 6) + ((((r >> 3) ^ (l & 7)) << 3) | (r & 7));
}
// bf16 [64 i][64 k]
__device__ __forceinline__ int gbidx(int i, int k) {
  return (i << 6) + ((((k >> 3) ^ (i & 7)) << 3) | (k & 7));
}
__device__ __forceinline__ short tobf(float x) {
  __hip_bfloat16 h = __float2bfloat16(x);
  return __builtin_bit_cast(short, h);
}
__device__ __forceinline__ float frombf(short s) {
  union { unsigned int u; float f; } c;
  c.u = ((unsigned int)(unsigned short)s) << 16;
  return c.f;
}
__device__ __forceinline__ unsigned int pack2(short lo, short hi) {
  return (unsigned int)(unsigned short)lo | ((unsigned int)(unsigned short)hi << 16);
}

// ---------------------------------------------------------------------------
// kG: blocks 0..63: G[i][j] = Wk_i . Wk_j (fp32); block 64: w = Wk*bk, bb = bk.bk
// grid 65 x 256
__global__ __launch_bounds__(256) void kG_pre(const float* __restrict__ Wk,
                                              const float* __restrict__ bk,
                                              float* __restrict__ ws) {
  const int t = threadIdx.x;
  const int blk = blockIdx.x;
  if (blk < 64) {
    const int j = t >> 2, kq = t & 3;
    const float4* a4 = (const float4*)(Wk + (size_t)blk * Hn) + kq * 32;
    const float4* b4 = (const float4*)(Wk + (size_t)j * Hn) + kq * 32;
    float s0 = 0.f, s1 = 0.f, s2 = 0.f, s3 = 0.f;
    #pragma unroll 8
    for (int h = 0; h < 32; ++h) {
      const float4 x = a4[h], y = b4[h];
      s0 += x.x * y.x; s1 += x.y * y.y; s2 += x.z * y.z; s3 += x.w * y.w;
    }
    float s = (s0 + s1) + (s2 + s3);
    s += __shfl_down(s, 2, 4);
    s += __shfl_down(s, 1, 4);
    if (kq == 0) ws[OFF_G + blk * 64 + j] = s;
    return;
  }
  const int i = t >> 2, kq = t & 3;
  const float4* a4 = (const float4*)(Wk + (size_t)i * Hn) + kq * 32;
  const float4* b4 = (const float4*)bk + kq * 32;
  float s0 = 0.f, s1 = 0.f, s2 = 0.f, s3 = 0.f;
  #pragma unroll 8
  for (int h = 0; h < 32; ++h) {
    const float4 x = a4[h], y = b4[h];
    s0 += x.x * y.x; s1 += x.y * y.y; s2 += x.z * y.z; s3 += x.w * y.w;
  }
  float s = (s0 + s1) + (s2 + s3);
  s += __shfl_down(s, 2, 4);
  s += __shfl_down(s, 1, 4);
  if (kq == 0) ws[OFF_W + i] = s;
  if (t < 4) {
    const float4* b4b = (const float4*)bk + t * 32;
    float q0 = 0.f, q1 = 0.f, q2 = 0.f, q3 = 0.f;
    #pragma unroll 8
    for (int h = 0; h < 32; ++h) {
      const float4 y = b4b[h];
      q0 += y.x * y.x; q1 += y.y * y.y; q2 += y.z * y.z; q3 += y.w * y.w;
    }
    float q = (q0 + q1) + (q2 + q3);
    q += __shfl_down(q, 2, 4);
    q += __shfl_down(q, 1, 4);
    if (t == 0) ws[OFF_BB] = q;
  }
}

// ---------------------------------------------------------------------------
// k1: per 128-row tile, fully on the matrix pipe (R14-proven); staging writes
//     packed to b32 (l-pairs within a granule).
// grid 512 x 256, 3 blocks/CU
__global__ __launch_bounds__(256, 3) void k1_stats(const float* __restrict__ hs,
                                                   float* __restrict__ ws) {
  __shared__ __align__(16) short XB[8192];   // bf16 X^T [r=64][l=128], swizzled
  __shared__ __align__(16) short XL[8192];   // bf16 X   [l=128][r=64], swizzled
  __shared__ __align__(16) short Gb[4096];   // bf16 G   [i=64][k=64], swizzled
  __shared__ __align__(16) float n2p[4][128];
  __shared__ __align__(16) float d1s[LT];
  __shared__ __align__(16) float wsh[64];

  const int t = threadIdx.x;
  const int idx = blockIdx.x;
  const int b = idx >> 6;
  const int seg = idx & 63;

  if (t < 64) wsh[t] = ws[OFF_W + t];
  const float bb = ws[OFF_BB];

  // stage G -> bf16 swizzled
  {
    const float4* G4 = (const float4*)(ws + OFF_G);
    #pragma unroll
    for (int p = 0; p < 4; ++p) {
      const int e = p * 256 + t;
      const float4 g = G4[e];
      const int i = e >> 4, k0 = (e & 15) << 2;
      short4 gp;
      gp.x = tobf(g.x); gp.y = tobf(g.y); gp.z = tobf(g.z); gp.w = tobf(g.w);
      *(short4*)&Gb[gbidx(i, k0)] = gp;
    }
  }
  // stage X -> XB (transposed, b32-packed l-pairs) + XL, bf16 swizzled
  {
    const float4* src = (const float4*)(hs + ((size_t)b * Ln + (size_t)seg * LT) * Rn);
    #pragma unroll
    for (int k = 0; k < 4; ++k) {
      const int g = k * 256 + t;            // 1024 pair-items
      const int c4 = g & 15;                // float4 col (16 per l-row)
      const int l = (g >> 4) * 2;           // even l
      const float4 v0 = src[(size_t)l * 16 + c4];
      const float4 v1 = src[(size_t)(l + 1) * 16 + c4];
      const int j0 = c4 * 4;
      const short a0 = tobf(v0.x), a1 = tobf(v0.y), a2 = tobf(v0.z), a3 = tobf(v0.w);
      const short b0 = tobf(v1.x), b1 = tobf(v1.y), b2 = tobf(v1.z), b3 = tobf(v1.w);
      *(unsigned int*)&XB[bidx(j0 + 0, l)] = pack2(a0, b0);
      *(unsigned int*)&XB[bidx(j0 + 1, l)] = pack2(a1, b1);
      *(unsigned int*)&XB[bidx(j0 + 2, l)] = pack2(a2, b2);
      *(unsigned int*)&XB[bidx(j0 + 3, l)] = pack2(a3, b3);
      short4 p0; p0.x = a0; p0.y = a1; p0.z = a2; p0.w = a3;
      short4 p1; p1.x = b0; p1.y = b1; p1.z = b2; p1.w = b3;
      *(short4*)&XL[xlidx(l, j0)] = p0;
      *(short4*)&XL[xlidx(l + 1, j0)] = p1;
    }
  }
  __syncthreads();

  const int lane = t & 63;
  const int w = t >> 6;              // wave -> i-strip [16w, 16w+16)
  const int lo = lane & 15;
  const int hi = lane >> 4;

  // T = G @ X (64x128, K=64) via MFMA; per-jt n2 partial
  {
    short8v ga[2];
    #pragma unroll
    for (int kc = 0; kc < 2; ++kc)
      ga[kc] = *(const short8v*)&Gb[gbidx(w * 16 + lo, kc * 32 + hi * 8)];
    #pragma unroll
    for (int jt = 0; jt < 8; ++jt) {
      f32x4v acc = {0.f, 0.f, 0.f, 0.f};
      #pragma unroll
      for (int kc = 0; kc < 2; ++kc) {
        const short8v xb = *(const short8v*)&XL[xlidx(jt * 16 + lo, kc * 32 + hi * 8)];
        acc = __builtin_amdgcn_mfma_f32_16x16x32_bf16(ga[kc], xb, acc, 0, 0, 0);
      }
      float p = 0.f;
      #pragma unroll
      for (int reg = 0; reg < 4; ++reg) {
        const int i = w * 16 + hi * 4 + reg;
        p += frombf(XB[bidx(i, jt * 16 + lo)]) * (acc[reg] + 2.0f * wsh[i]);
      }
      p += __shfl_xor(p, 16, 64);
      p += __shfl_xor(p, 32, 64);
      if (hi == 0) n2p[w][jt * 16 + lo] = p;
    }
  }
  __syncthreads();
  if (t < LT) {
    const float n2 = fmaxf(bb + ((n2p[0][t] + n2p[1][t]) + (n2p[2][t] + n2p[3][t])), 0.0f);
    d1s[t] = 1.0f / fmaxf(sqrtf(n2), 1e-12f);
  }
  __syncthreads();

  float* P = ws + OFF_STATS + (size_t)idx * PS;

  float sg1 = 0.f, sg2 = 0.f;
  if (t < 64) {
    const float da = d1s[t], db = d1s[t + 64];
    float a1 = da + db;
    float a2 = da * da + db * db;
    #pragma unroll
    for (int off = 32; off > 0; off >>= 1) {
      a1 += __shfl_down(a1, off, 64);
      a2 += __shfl_down(a2, off, 64);
    }
    sg1 = a1; sg2 = a2;
  }

  // u1/u2 partials (fp32, from XB + d1s)
  {
    const int r = t >> 2;
    const int lq = (t & 3) * 32;
    float u1p = 0.f, u2p = 0.f;
    #pragma unroll
    for (int g = 0; g < 4; ++g) {
      const int l0 = lq + g * 8;
      const short8v xv = *(const short8v*)&XB[bidx(r, l0)];
      #pragma unroll
      for (int e = 0; e < 8; ++e) {
        const float d = d1s[l0 + e];
        const float x = frombf(xv[e]);
        u1p += d * x;
        u2p += d * d * x;
      }
    }
    u1p += __shfl_down(u1p, 2, 4); u1p += __shfl_down(u1p, 1, 4);
    u2p += __shfl_down(u2p, 2, 4); u2p += __shfl_down(u2p, 1, 4);
    if ((t & 3) == 0) {
      P[4096 + r] = u1p;
      P[4160 + r] = u2p;
    }
  }

  // A1 = (dX)^T X, A2 = (d^2 X)^T X via MFMA; A-side diag-weighted only. K=128.
  {
    short* P1s = (short*)P;             // bf16 A1 partial [64*64]
    short* P2s = (short*)(P + 2048);    // bf16 A2 partial [64*64]
    short8v ea[4], fa[4];
    #pragma unroll
    for (int kc = 0; kc < 4; ++kc) {
      const short8v xa = *(const short8v*)&XB[bidx(w * 16 + lo, kc * 32 + hi * 8)];
      #pragma unroll
      for (int e = 0; e < 8; ++e) {
        const float de = d1s[kc * 32 + hi * 8 + e];
        const float dx = de * frombf(xa[e]);
        ea[kc][e] = tobf(dx);
        fa[kc][e] = tobf(de * dx);
      }
    }
    #pragma unroll
    for (int jt = 0; jt < 4; ++jt) {
      f32x4v a1 = {0.f, 0.f, 0.f, 0.f};
      f32x4v a2 = {0.f, 0.f, 0.f, 0.f};
      #pragma unroll
      for (int kc = 0; kc < 4; ++kc) {
        const short8v xb = *(const short8v*)&XB[bidx(jt * 16 + lo, kc * 32 + hi * 8)];
        a1 = __builtin_amdgcn_mfma_f32_16x16x32_bf16(ea[kc], xb, a1, 0, 0, 0);
        a2 = __builtin_amdgcn_mfma_f32_16x16x32_bf16(fa[kc], xb, a2, 0, 0, 0);
      }
      #pragma unroll
      for (int reg = 0; reg < 4; ++reg) {
        const int off = (w * 16 + hi * 4 + reg) * 64 + jt * 16 + lo;
        P1s[off] = tobf(a1[reg]);
        P2s[off] = tobf(a2[reg]);
      }
    }
  }

  if (t == 0) { P[4224] = sg1; P[4225] = sg2; }
}

// ---------------------------------------------------------------------------
// k1bM: blocks 0..255  = M/c1 partial GEMM (R13-proven, verbatim);
//       blocks 256..511 = STATS reduce (bf16 A-partials).
// grid 512 x 256
__global__ __launch_bounds__(256) void k1bM(const float* __restrict__ Wk,
                                            const float* __restrict__ bk,
                                            const float* __restrict__ C,
                                            float* __restrict__ ws) {
  __shared__ __align__(16) float WkS[64][132];
  __shared__ __align__(16) float Cs[128][68];
  __shared__ __align__(16) float bks[128];

  const int t = threadIdx.x;
  const int blk = blockIdx.x;

  if (blk < 256) {
    const int m = blk;
    const int b = m >> 5;
    const int rem = m & 31;
    const int hc = rem >> 3;
    const int ds = rem & 7;
    const int h0 = hc * 128;
    const int d04 = ds * 16;

    const float4* Wk4 = (const float4*)Wk;
    const float4* C4b = (const float4*)(C + (size_t)b * Hn * Hn);
    #pragma unroll
    for (int p = 0; p < 8; ++p) {
      const int e = p * 256 + t;
      const int r = e >> 5, c4 = e & 31;
      *(float4*)&WkS[r][c4 * 4] = Wk4[(size_t)r * 128 + (h0 >> 2) + c4];
    }
    #pragma unroll
    for (int p = 0; p < 8; ++p) {
      const int e = p * 256 + t;
      const int r = e >> 4, c4 = e & 15;
      *(float4*)&Cs[r][c4 * 4] = C4b[(size_t)(h0 + r) * 128 + d04 + c4];
    }
    if (t < 32) *(float4*)&bks[t * 4] = ((const float4*)&bk[h0])[t];
    __syncthreads();

    const int ig = t >> 4;
    const int i4 = ig * 4;
    const int d4 = t & 15;
    float4 acc0 = make_float4(0.f, 0.f, 0.f, 0.f);
    float4 acc1 = make_float4(0.f, 0.f, 0.f, 0.f);
    float4 acc2 = make_float4(0.f, 0.f, 0.f, 0.f);
    float4 acc3 = make_float4(0.f, 0.f, 0.f, 0.f);
    float4 c1a  = make_float4(0.f, 0.f, 0.f, 0.f);

    #pragma unroll 4
    for (int h4 = 0; h4 < 128; h4 += 4) {
      const float4 w0 = *(const float4*)&WkS[i4 + 0][h4];
      const float4 w1 = *(const float4*)&WkS[i4 + 1][h4];
      const float4 w2 = *(const float4*)&WkS[i4 + 2][h4];
      const float4 w3 = *(const float4*)&WkS[i4 + 3][h4];
      const float4 c0 = *(const float4*)&Cs[h4 + 0][d4 * 4];
      const float4 c1 = *(const float4*)&Cs[h4 + 1][d4 * 4];
      const float4 c2 = *(const float4*)&Cs[h4 + 2][d4 * 4];
      const float4 c3 = *(const float4*)&Cs[h4 + 3][d4 * 4];

      acc0.x += w0.x*c0.x + w0.y*c1.x + w0.z*c2.x + w0.w*c3.x;
      acc0.y += w0.x*c0.y + w0.y*c1.y + w0.z*c2.y + w0.w*c3.y;
      acc0.z += w0.x*c0.z + w0.y*c1.z + w0.z*c2.z + w0.w*c3.z;
      acc0.w += w0.x*c0.w + w0.y*c1.w + w0.z*c2.w + w0.w*c3.w;
      acc1.x += w1.x*c0.x + w1.y*c1.x + w1.z*c2.x + w1.w*c3.x;
      acc1.y += w1.x*c0.y + w1.y*c1.y + w1.z*c2.y + w1.w*c3.y;
      acc1.z += w1.x*c0.z + w1.y*c1.z + w1.z*c2.z + w1.w*c3.z;
      acc1.w += w1.x*c0.w + w1.y*c1.w + w1.z*c2.w + w1.w*c3.w;
      acc2.x += w2.x*c0.x + w2.y*c1.x + w2.z*c2.x + w2.w*c3.x;
      acc2.y += w2.x*c0.y + w2.y*c1.y + w2.z*c2.y + w2.w*c3.y;
      acc2.z += w2.x*c0.z + w2.y*c1.z + w2.z*c2.z + w2.w*c3.z;
      acc2.w += w2.x*c0.w + w2.y*c1.w + w2.z*c2.w + w2.w*c3.w;
      acc3.x += w3.x*c0.x + w3.y*c1.x + w3.z*c2.x + w3.w*c3.x;
      acc3.y += w3.x*c0.y + w3.y*c1.y + w3.z*c2.y + w3.w*c3.y;
      acc3.z += w3.x*c0.z + w3.y*c1.z + w3.z*c2.z + w3.w*c3.z;
      acc3.w += w3.x*c0.w + w3.y*c1.w + w3.z*c2.w + w3.w*c3.w;

      if (ig == 0) {
        const float b0 = bks[h4 + 0], b1 = bks[h4 + 1];
        const float b2 = bks[h4 + 2], b3 = bks[h4 + 3];
        c1a.x += b0*c0.x + b1*c1.x + b2*c2.x + b3*c3.x;
        c1a.y += b0*c0.y + b1*c1.y + b2*c2.y + b3*c3.y;
        c1a.z += b0*c0.z + b1*c1.z + b2*c2.z + b3*c3.z;
        c1a.w += b0*c0.w + b1*c1.w + b2*c2.w + b3*c3.w;
      }
    }

    float4* MP4 = (float4*)(ws + OFF_MP);
    const size_t base = (size_t)(b * NHC + hc) * 64;
    MP4[(base + i4 + 0) * 128 + d04 + d4] = acc0;
    MP4[(base + i4 + 1) * 128 + d04 + d4] = acc1;
    MP4[(base + i4 + 2) * 128 + d04 + d4] = acc2;
    MP4[(base + i4 + 3) * 128 + d04 + d4] = acc3;
    if (ig == 0) {
      float4* c14 = (float4*)(ws + OFF_C1P);
      c14[(size_t)(b * NHC + hc) * 128 + d04 + d4] = c1a;
    }
    return;
  }

  // ---- k1b: reduce 64 STATS partials per batch (A1/A2 bf16, u/sig fp32) ----
  const int rblk = blk - 256;
  const int b = rblk >> 5, sel = (rblk >> 4) & 1, q = rblk & 15;
  const short* SBs = (const short*)(ws + OFF_STATS + (size_t)b * 64 * PS + (sel ? 2048 : 0));
  float* dst = ws + (sel ? OFF_A2R : OFF_A1R) + (size_t)b * 4096;
  const int e = q * 256 + t;
  float s = 0.f;
  #pragma unroll 8
  for (int p = 0; p < 64; ++p) s += frombf(SBs[(size_t)p * (PS * 2) + e]);
  dst[e] = s;
  if (sel == 0 && q == 0) {
    const float* UB = ws + OFF_STATS + (size_t)b * 64 * PS;
    if (t < 64) {
      float s2 = 0.f;
      #pragma unroll 8
      for (int p = 0; p < 64; ++p) s2 += UB[(size_t)p * PS + 4096 + t];
      ws[OFF_U1R + b * 64 + t] = s2;
    } else if (t < 128) {
      const int i = t - 64;
      float s2 = 0.f;
      #pragma unroll 8
      for (int p = 0; p < 64; ++p) s2 += UB[(size_t)p * PS + 4160 + i];
      ws[OFF_U2R + b * 64 + i] = s2;
    } else if (t == 128) {
      float s1 = 0.f, s2 = 0.f;
      for (int p = 0; p < 64; ++p) {
        s1 += UB[(size_t)p * PS + 4224];
        s2 += UB[(size_t)p * PS + 4225];
      }
      ws[OFF_SIG + b * 2] = s1;
      ws[OFF_SIG + b * 2 + 1] = s2;
    }
  }
}

// ---------------------------------------------------------------------------
// k2p: Td = A1 @ Wv - A2 @ M  (M = sum of 4 h-partials); 16-wide d strips.
//      p1 = Wk^T u1, p2 = Wk^T u2, q1 = Wv^T u1, g = u2^T M
// grid 256 (= b(8) x ds(32, 16-wide)) x 256
__global__ __launch_bounds__(256) void k2p_td(const float* __restrict__ Wk,
                                              const float* __restrict__ Wv,
                                              float* __restrict__ ws) {
  __shared__ __align__(16) float A1s[64][66];
  __shared__ __align__(16) float A2s[64][66];
  __shared__ __align__(16) float Wvt[64][20];
  __shared__ __align__(16) float Mt[64][20];
  __shared__ __align__(16) float u1s[64];
  __shared__ __align__(16) float u2s[64];

  const int t = threadIdx.x;
  const int blk = blockIdx.x;
  const int b = blk >> 5;
  const int ds = blk & 31;
  const int d04 = ds * 4;                     // float4 offset of 16-wide strip

  const float4* A1R4 = (const float4*)(ws + OFF_A1R + (size_t)b * 4096);
  const float4* A2R4 = (const float4*)(ws + OFF_A2R + (size_t)b * 4096);
  #pragma unroll
  for (int p = 0; p < 4; ++p) {
    const int idx = p * 256 + t;
    const int r = idx >> 4, c0 = (idx & 15) * 4;
    *(float4*)&A1s[r][c0] = A1R4[idx];
    *(float4*)&A2s[r][c0] = A2R4[idx];
  }
  const float4* Wv4 = (const float4*)Wv;
  const float4* MP4 = (const float4*)(ws + OFF_MP);
  {
    const int r = t >> 2, c4 = t & 3;          // 256 float4: 1 per thread
    *(float4*)&Wvt[r][c4 * 4] = Wv4[(size_t)r * 128 + d04 + c4];
    float4 m = MP4[((size_t)(b * NHC + 0) * 64 + r) * 128 + d04 + c4];
    #pragma unroll
    for (int q = 1; q < NHC; ++q) {
      const float4 mq = MP4[((size_t)(b * NHC + q) * 64 + r) * 128 + d04 + c4];
      m.x += mq.x; m.y += mq.y; m.z += mq.z; m.w += mq.w;
    }
    *(float4*)&Mt[r][c4 * 4] = m;
  }
  if (t < 16) {
    *(float4*)&u1s[t * 4] = *(const float4*)(ws + OFF_U1R + b * 64 + t * 4);
  } else if (t < 32) {
    const int i = t - 16;
    *(float4*)&u2s[i * 4] = *(const float4*)(ws + OFF_U2R + b * 64 + i * 4);
  }
  __syncthreads();

  const int ig = t >> 2;                       // row 0..63
  const int tj4 = t & 3;
  float4 acc0 = make_float4(0.f, 0.f, 0.f, 0.f);
  #pragma unroll 8
  for (int j = 0; j < 64; ++j) {
    const float4 wv = *(const float4*)&Wvt[j][tj4 * 4];
    const float4 mv = *(const float4*)&Mt[j][tj4 * 4];
    const float a10 = A1s[ig][j], a20 = A2s[ig][j];
    acc0.x += a10 * wv.x - a20 * mv.x; acc0.y += a10 * wv.y - a20 * mv.y;
    acc0.z += a10 * wv.z - a20 * mv.z; acc0.w += a10 * wv.w - a20 * mv.w;
  }
  float4* Td4 = (float4*)(ws + OFF_TD + (size_t)b * 64 * Hn);
  Td4[(size_t)ig * 128 + d04 + tj4] = acc0;

  if (t < 16) {
    const int d = ds * 16 + t;
    float q1 = 0.f, g = 0.f;
    #pragma unroll 8
    for (int i = 0; i < 64; ++i) {
      q1 += u1s[i] * Wvt[i][t];
      g  += u2s[i] * Mt[i][t];
    }
    ws[OFF_Q1 + (size_t)b * Hn + d] = q1;
    ws[OFF_GV + (size_t)b * Hn + d] = g;
  } else if (t < 32) {
    const int h = ds * 16 + (t - 16);
    float p1 = 0.f, p2 = 0.f;
    #pragma unroll 8
    for (int i = 0; i < 64; ++i) {
      const float wv = Wk[(size_t)i * Hn + h];
      p1 += wv * u1s[i];
      p2 += wv * u2s[i];
    }
    ws[OFF_P1 + (size_t)b * Hn + h] = p1;
    ws[OFF_P2 + (size_t)b * Hn + h] = p2;
  }
}

// ---------------------------------------------------------------------------
// k4: out = C + Wk^T Td + (p1 + sig1*bk) (x) bv + bk (x) (q1 - g - sig2*c1) - p2 (x) c1
// grid 1024 (= b(8) x hstrip(8, 64-wide) x dstrip(16, 32-wide)) x 256
__global__ __launch_bounds__(256) void k4_out(const float* __restrict__ C,
                                              const float* __restrict__ Wk,
                                              const float* __restrict__ bk,
                                              const float* __restrict__ bv,
                                              const float* __restrict__ ws,
                                              float* __restrict__ out) {
  __shared__ __align__(16) float Tds[64][36];
  __shared__ __align__(16) float Wks[64][68];
  __shared__ float phs[64], bks[64], p2s[64];
  __shared__ float bvs[32], terms[32], c1s[32];

  const int t = threadIdx.x;
  const int blk = blockIdx.x;
  const int b = blk >> 7;
  const int rem = blk & 127;
  const int hs0 = (rem >> 4) * 64;
  const int d04 = (rem & 15) * 8;             // float4 offset of 32-wide d strip
  const float sg1 = ws[OFF_SIG + b * 2];
  const float sg2 = ws[OFF_SIG + b * 2 + 1];

  const float4* TdG4 = (const float4*)(ws + OFF_TD + (size_t)b * 64 * Hn);
  const float4* Wk4 = (const float4*)Wk;
  #pragma unroll
  for (int p = 0; p < 2; ++p) {
    const int e = p * 256 + t;                // 512 float4 (64 x 8)
    const int r = e >> 3, c4 = e & 7;
    *(float4*)&Tds[r][c4 * 4] = TdG4[(size_t)r * 128 + d04 + c4];
  }
  #pragma unroll
  for (int p = 0; p < 4; ++p) {
    const int e = p * 256 + t;                // 1024 float4 (64 x 16)
    const int r = e >> 4, c4 = e & 15;
    *(float4*)&Wks[r][c4 * 4] = Wk4[(size_t)r * 128 + (hs0 >> 2) + c4];
  }
  if (t < 64) {
    const int h = hs0 + t;
    const float bkv = bk[h];
    bks[t] = bkv;
    phs[t] = ws[OFF_P1 + (size_t)b * Hn + h] + sg1 * bkv;
    p2s[t] = ws[OFF_P2 + (size_t)b * Hn + h];
  } else if (t < 96) {
    const int dd = t - 64;
    const int d = d04 * 4 + dd;
    float c1 = 0.f;
    #pragma unroll
    for (int q = 0; q < NHC; ++q)
      c1 += ws[OFF_C1P + (size_t)(b * NHC + q) * Hn + d];
    c1s[dd] = c1;
    bvs[dd] = bv[d];
    terms[dd] = ws[OFF_Q1 + (size_t)b * Hn + d] - ws[OFF_GV + (size_t)b * Hn + d] - sg2 * c1;
  }
  __syncthreads();

  const int ti = t >> 3;   // rows 2ti, 2ti+1
  const int tj4 = t & 7;   // d float4 within strip
  float4 acc0 = make_float4(0.f, 0.f, 0.f, 0.f);
  float4 acc1 = make_float4(0.f, 0.f, 0.f, 0.f);
  for (int j = 0; j < 64; ++j) {
    const float4 td4 = *(const float4*)&Tds[j][tj4 * 4];
    const float w0 = Wks[j][ti * 2];
    const float w1 = Wks[j][ti * 2 + 1];
    acc0.x += w0 * td4.x; acc0.y += w0 * td4.y; acc0.z += w0 * td4.z; acc0.w += w0 * td4.w;
    acc1.x += w1 * td4.x; acc1.y += w1 * td4.y; acc1.z += w1 * td4.z; acc1.w += w1 * td4.w;
  }

  const float4* C4b = (const float4*)(C + (size_t)b * Hn * Hn);
  float4* out4 = (float4*)(out + (size_t)b * Hn * Hn);
  const float4 bv4 = *(const float4*)&bvs[tj4 * 4];
  const float4 tm4 = *(const float4*)&terms[tj4 * 4];
  const float4 c14 = *(const float4*)&c1s[tj4 * 4];
  #pragma unroll
  for (int a = 0; a < 2; ++a) {
    const int hh = ti * 2 + a;
    const int h = hs0 + hh;
    const float4 acc = a ? acc1 : acc0;
    const float4 c = C4b[(size_t)h * 128 + d04 + tj4];
    const float ph = phs[hh], bkh = bks[hh], p2h = p2s[hh];
    float4 o;
    o.x = c.x + acc.x + ph * bv4.x + bkh * tm4.x - p2h * c14.x;
    o.y = c.y + acc.y + ph * bv4.y + bkh * tm4.y - p2h * c14.y;
    o.z = c.z + acc.z + ph * bv4.z + bkh * tm4.z - p2h * c14.z;
    o.w = c.w + acc.w + ph * bv4.w + bkh * tm4.w - p2h * c14.w;
    out4[(size_t)h * 128 + d04 + tj4] = o;
  }
}

// ---------------------------------------------------------------------------
extern "C" void kernel_launch(void* const* d_in, const int* in_sizes, int n_in,
                              void* d_out, int out_size, void* d_ws, size_t ws_size,
                              hipStream_t stream) {
  const float* hs = (const float*)d_in[0];
  const float* C  = (const float*)d_in[1];
  const float* Wk = (const float*)d_in[2];
  const float* bk = (const float*)d_in[3];
  const float* Wv = (const float*)d_in[4];
  const float* bv = (const float*)d_in[5];
  float* out = (float*)d_out;
  float* ws = (float*)d_ws;
  (void)in_sizes; (void)n_in; (void)out_size; (void)ws_size;

  hipLaunchKernelGGL(kG_pre,   dim3(65),   dim3(256), 0, stream, Wk, bk, ws);
  hipLaunchKernelGGL(k1_stats, dim3(512),  dim3(256), 0, stream, hs, ws);
  hipLaunchKernelGGL(k1bM,     dim3(512),  dim3(256), 0, stream, Wk, bk, C, ws);
  hipLaunchKernelGGL(k2p_td,   dim3(256),  dim3(256), 0, stream, Wk, Wv, ws);
  hipLaunchKernelGGL(k4_out,   dim3(1024), dim3(256), 0, stream, C, Wk, bk, bv, ws, out);
}

// Round 17
// 50.570 us; speedup vs baseline: 1.0158x; 1.0158x over previous
//
#include <hip/hip_runtime.h>
#include <hip/hip_bf16.h>
#include <math.h>

namespace {
constexpr int Bn = 8;
constexpr int Ln = 8192;
constexpr int Rn = 64;
constexpr int Hn = 512;
constexpr int LT = 128;
constexpr int NSEG = Ln / LT;            // 64 segments per batch
constexpr int NK1 = Bn * NSEG;           // 512 k1 blocks
constexpr int NHC = 4;                   // M h-chunks (128 h each)

// workspace float offsets
// per-k1-block partial: A1 bf16[4096] (2048 f), A2 bf16[4096] (2048 f),
//                       u1 f32[64], u2 f32[64], sig f32[2], pad
constexpr size_t PS        = 4352;
constexpr size_t OFF_G     = 0;                                   // fp32 G 64x64
constexpr size_t OFF_W     = 4096;                                // 64
constexpr size_t OFF_BB    = 4160;                                // 1 (+pad)
constexpr size_t OFF_STATS = 4224;                                // NK1 * PS
constexpr size_t OFF_A1R   = OFF_STATS + (size_t)NK1 * PS;        // B*4096
constexpr size_t OFF_A2R   = OFF_A1R + (size_t)Bn * 4096;         // B*4096
constexpr size_t OFF_U1R   = OFF_A2R + (size_t)Bn * 4096;         // B*64
constexpr size_t OFF_U2R   = OFF_U1R + (size_t)Bn * 64;           // B*64
constexpr size_t OFF_SIG   = OFF_U2R + (size_t)Bn * 64;           // B*2 (pad 64)
constexpr size_t OFF_MP    = OFF_SIG + 64;                        // B*NHC*64*H (M h-partials)
constexpr size_t OFF_C1P   = OFF_MP + (size_t)Bn * NHC * 64 * Hn; // B*NHC*H
constexpr size_t OFF_TD    = OFF_C1P + (size_t)Bn * NHC * Hn;     // B*64*H
constexpr size_t OFF_P1    = OFF_TD + (size_t)Bn * 64 * Hn;       // B*H
constexpr size_t OFF_P2    = OFF_P1 + (size_t)Bn * Hn;            // B*H
constexpr size_t OFF_Q1    = OFF_P2 + (size_t)Bn * Hn;            // B*H
constexpr size_t OFF_GV    = OFF_Q1 + (size_t)Bn * Hn;            // B*H (g = u2^T M)
}

using short8v = __attribute__((ext_vector_type(8))) short;
using f32x4v  = __attribute__((ext_vector_type(4))) float;

// bf16 [64 r][128 l], 8-elem granules XOR-swizzled by row (HW-validated R8/R9)
__device__ __forceinline__ int bidx(int r, int l) {
  return (r << 7) + ((((l >> 3) ^ (r & 7)) << 3) | (l & 7));
}
// bf16 [128 l][64 r]
__device__ __forceinline__ int xlidx(int l, int r) {
  return (l << 6) + ((((r >> 3) ^ (l & 7)) << 3) | (r & 7));
}
// bf16 [64 i][64 k]
__device__ __forceinline__ int gbidx(int i, int k) {
  return (i << 6) + ((((k >> 3) ^ (i & 7)) << 3) | (k & 7));
}
__device__ __forceinline__ short tobf(float x) {
  __hip_bfloat16 h = __float2bfloat16(x);
  return __builtin_bit_cast(short, h);
}
__device__ __forceinline__ float frombf(short s) {
  union { unsigned int u; float f; } c;
  c.u = ((unsigned int)(unsigned short)s) << 16;
  return c.f;
}
__device__ __forceinline__ unsigned int pack2(short lo, short hi) {
  return (unsigned int)(unsigned short)lo | ((unsigned int)(unsigned short)hi << 16);
}

// ---------------------------------------------------------------------------
// kG: blocks 0..63: G[i][j] = Wk_i . Wk_j (fp32); block 64: w = Wk*bk, bb = bk.bk
// grid 65 x 256
__global__ __launch_bounds__(256) void kG_pre(const float* __restrict__ Wk,
                                              const float* __restrict__ bk,
                                              float* __restrict__ ws) {
  const int t = threadIdx.x;
  const int blk = blockIdx.x;
  if (blk < 64) {
    const int j = t >> 2, kq = t & 3;
    const float4* a4 = (const float4*)(Wk + (size_t)blk * Hn) + kq * 32;
    const float4* b4 = (const float4*)(Wk + (size_t)j * Hn) + kq * 32;
    float s0 = 0.f, s1 = 0.f, s2 = 0.f, s3 = 0.f;
    #pragma unroll 8
    for (int h = 0; h < 32; ++h) {
      const float4 x = a4[h], y = b4[h];
      s0 += x.x * y.x; s1 += x.y * y.y; s2 += x.z * y.z; s3 += x.w * y.w;
    }
    float s = (s0 + s1) + (s2 + s3);
    s += __shfl_down(s, 2, 4);
    s += __shfl_down(s, 1, 4);
    if (kq == 0) ws[OFF_G + blk * 64 + j] = s;
    return;
  }
  const int i = t >> 2, kq = t & 3;
  const float4* a4 = (const float4*)(Wk + (size_t)i * Hn) + kq * 32;
  const float4* b4 = (const float4*)bk + kq * 32;
  float s0 = 0.f, s1 = 0.f, s2 = 0.f, s3 = 0.f;
  #pragma unroll 8
  for (int h = 0; h < 32; ++h) {
    const float4 x = a4[h], y = b4[h];
    s0 += x.x * y.x; s1 += x.y * y.y; s2 += x.z * y.z; s3 += x.w * y.w;
  }
  float s = (s0 + s1) + (s2 + s3);
  s += __shfl_down(s, 2, 4);
  s += __shfl_down(s, 1, 4);
  if (kq == 0) ws[OFF_W + i] = s;
  if (t < 4) {
    const float4* b4b = (const float4*)bk + t * 32;
    float q0 = 0.f, q1 = 0.f, q2 = 0.f, q3 = 0.f;
    #pragma unroll 8
    for (int h = 0; h < 32; ++h) {
      const float4 y = b4b[h];
      q0 += y.x * y.x; q1 += y.y * y.y; q2 += y.z * y.z; q3 += y.w * y.w;
    }
    float q = (q0 + q1) + (q2 + q3);
    q += __shfl_down(q, 2, 4);
    q += __shfl_down(q, 1, 4);
    if (t == 0) ws[OFF_BB] = q;
  }
}

// ---------------------------------------------------------------------------
// k1: per 128-row tile, fully on the matrix pipe (R14-proven).
//   A1 = (dX)^T X, A2 = (d^2 X)^T X  -- diag weights on the A operand only.
//   Partials stored bf16.
// grid 512 x 256, 3 blocks/CU
__global__ __launch_bounds__(256, 3) void k1_stats(const float* __restrict__ hs,
                                                   float* __restrict__ ws) {
  __shared__ __align__(16) short XB[8192];   // bf16 X^T [r=64][l=128], swizzled
  __shared__ __align__(16) short XL[8192];   // bf16 X   [l=128][r=64], swizzled
  __shared__ __align__(16) short Gb[4096];   // bf16 G   [i=64][k=64], swizzled
  __shared__ __align__(16) float n2p[4][128];
  __shared__ __align__(16) float d1s[LT];
  __shared__ __align__(16) float wsh[64];

  const int t = threadIdx.x;
  const int idx = blockIdx.x;
  const int b = idx >> 6;
  const int seg = idx & 63;

  if (t < 64) wsh[t] = ws[OFF_W + t];
  const float bb = ws[OFF_BB];

  // stage G -> bf16 swizzled
  {
    const float4* G4 = (const float4*)(ws + OFF_G);
    #pragma unroll
    for (int p = 0; p < 4; ++p) {
      const int e = p * 256 + t;
      const float4 g = G4[e];
      const int i = e >> 4, k0 = (e & 15) << 2;
      short4 gp;
      gp.x = tobf(g.x); gp.y = tobf(g.y); gp.z = tobf(g.z); gp.w = tobf(g.w);
      *(short4*)&Gb[gbidx(i, k0)] = gp;
    }
  }
  // stage X -> XB (transposed, b32-packed l-pairs) + XL, bf16 swizzled
  {
    const float4* src = (const float4*)(hs + ((size_t)b * Ln + (size_t)seg * LT) * Rn);
    #pragma unroll
    for (int k = 0; k < 4; ++k) {
      const int g = k * 256 + t;            // 1024 pair-items
      const int c4 = g & 15;                // float4 col (16 per l-row)
      const int l = (g >> 4) * 2;           // even l
      const float4 v0 = src[(size_t)l * 16 + c4];
      const float4 v1 = src[(size_t)(l + 1) * 16 + c4];
      const int j0 = c4 * 4;
      const short a0 = tobf(v0.x), a1 = tobf(v0.y), a2 = tobf(v0.z), a3 = tobf(v0.w);
      const short b0 = tobf(v1.x), b1 = tobf(v1.y), b2 = tobf(v1.z), b3 = tobf(v1.w);
      *(unsigned int*)&XB[bidx(j0 + 0, l)] = pack2(a0, b0);
      *(unsigned int*)&XB[bidx(j0 + 1, l)] = pack2(a1, b1);
      *(unsigned int*)&XB[bidx(j0 + 2, l)] = pack2(a2, b2);
      *(unsigned int*)&XB[bidx(j0 + 3, l)] = pack2(a3, b3);
      short4 p0; p0.x = a0; p0.y = a1; p0.z = a2; p0.w = a3;
      short4 p1; p1.x = b0; p1.y = b1; p1.z = b2; p1.w = b3;
      *(short4*)&XL[xlidx(l, j0)] = p0;
      *(short4*)&XL[xlidx(l + 1, j0)] = p1;
    }
  }
  __syncthreads();

  const int lane = t & 63;
  const int w = t >> 6;              // wave -> i-strip [16w, 16w+16)
  const int lo = lane & 15;
  const int hi = lane >> 4;

  // T = G @ X (64x128, K=64) via MFMA; per-jt n2 partial
  {
    short8v ga[2];
    #pragma unroll
    for (int kc = 0; kc < 2; ++kc)
      ga[kc] = *(const short8v*)&Gb[gbidx(w * 16 + lo, kc * 32 + hi * 8)];
    #pragma unroll
    for (int jt = 0; jt < 8; ++jt) {
      f32x4v acc = {0.f, 0.f, 0.f, 0.f};
      #pragma unroll
      for (int kc = 0; kc < 2; ++kc) {
        const short8v xb = *(const short8v*)&XL[xlidx(jt * 16 + lo, kc * 32 + hi * 8)];
        acc = __builtin_amdgcn_mfma_f32_16x16x32_bf16(ga[kc], xb, acc, 0, 0, 0);
      }
      float p = 0.f;
      #pragma unroll
      for (int reg = 0; reg < 4; ++reg) {
        const int i = w * 16 + hi * 4 + reg;
        p += frombf(XB[bidx(i, jt * 16 + lo)]) * (acc[reg] + 2.0f * wsh[i]);
      }
      p += __shfl_xor(p, 16, 64);
      p += __shfl_xor(p, 32, 64);
      if (hi == 0) n2p[w][jt * 16 + lo] = p;
    }
  }
  __syncthreads();
  if (t < LT) {
    const float n2 = fmaxf(bb + ((n2p[0][t] + n2p[1][t]) + (n2p[2][t] + n2p[3][t])), 0.0f);
    d1s[t] = 1.0f / fmaxf(sqrtf(n2), 1e-12f);
  }
  __syncthreads();

  float* P = ws + OFF_STATS + (size_t)idx * PS;

  float sg1 = 0.f, sg2 = 0.f;
  if (t < 64) {
    const float da = d1s[t], db = d1s[t + 64];
    float a1 = da + db;
    float a2 = da * da + db * db;
    #pragma unroll
    for (int off = 32; off > 0; off >>= 1) {
      a1 += __shfl_down(a1, off, 64);
      a2 += __shfl_down(a2, off, 64);
    }
    sg1 = a1; sg2 = a2;
  }

  // u1/u2 partials (fp32, from XB + d1s)
  {
    const int r = t >> 2;
    const int lq = (t & 3) * 32;
    float u1p = 0.f, u2p = 0.f;
    #pragma unroll
    for (int g = 0; g < 4; ++g) {
      const int l0 = lq + g * 8;
      const short8v xv = *(const short8v*)&XB[bidx(r, l0)];
      #pragma unroll
      for (int e = 0; e < 8; ++e) {
        const float d = d1s[l0 + e];
        const float x = frombf(xv[e]);
        u1p += d * x;
        u2p += d * d * x;
      }
    }
    u1p += __shfl_down(u1p, 2, 4); u1p += __shfl_down(u1p, 1, 4);
    u2p += __shfl_down(u2p, 2, 4); u2p += __shfl_down(u2p, 1, 4);
    if ((t & 3) == 0) {
      P[4096 + r] = u1p;
      P[4160 + r] = u2p;
    }
  }

  // A1 = (dX)^T X, A2 = (d^2 X)^T X via MFMA; A-side diag-weighted only. K=128.
  {
    short* P1s = (short*)P;             // bf16 A1 partial [64*64]
    short* P2s = (short*)(P + 2048);    // bf16 A2 partial [64*64]
    short8v ea[4], fa[4];
    #pragma unroll
    for (int kc = 0; kc < 4; ++kc) {
      const short8v xa = *(const short8v*)&XB[bidx(w * 16 + lo, kc * 32 + hi * 8)];
      #pragma unroll
      for (int e = 0; e < 8; ++e) {
        const float de = d1s[kc * 32 + hi * 8 + e];
        const float dx = de * frombf(xa[e]);
        ea[kc][e] = tobf(dx);
        fa[kc][e] = tobf(de * dx);
      }
    }
    #pragma unroll
    for (int jt = 0; jt < 4; ++jt) {
      f32x4v a1 = {0.f, 0.f, 0.f, 0.f};
      f32x4v a2 = {0.f, 0.f, 0.f, 0.f};
      #pragma unroll
      for (int kc = 0; kc < 4; ++kc) {
        const short8v xb = *(const short8v*)&XB[bidx(jt * 16 + lo, kc * 32 + hi * 8)];
        a1 = __builtin_amdgcn_mfma_f32_16x16x32_bf16(ea[kc], xb, a1, 0, 0, 0);
        a2 = __builtin_amdgcn_mfma_f32_16x16x32_bf16(fa[kc], xb, a2, 0, 0, 0);
      }
      #pragma unroll
      for (int reg = 0; reg < 4; ++reg) {
        const int off = (w * 16 + hi * 4 + reg) * 64 + jt * 16 + lo;
        P1s[off] = tobf(a1[reg]);
        P2s[off] = tobf(a2[reg]);
      }
    }
  }

  if (t == 0) { P[4224] = sg1; P[4225] = sg2; }
}

// ---------------------------------------------------------------------------
// k1bM: blocks 0..255  = M/c1 partial GEMM (R13-proven, verbatim);
//       blocks 256..511 = STATS reduce (bf16 A-partials).
// grid 512 x 256
__global__ __launch_bounds__(256) void k1bM(const float* __restrict__ Wk,
                                            const float* __restrict__ bk,
                                            const float* __restrict__ C,
                                            float* __restrict__ ws) {
  __shared__ __align__(16) float WkS[64][132];
  __shared__ __align__(16) float Cs[128][68];
  __shared__ __align__(16) float bks[128];

  const int t = threadIdx.x;
  const int blk = blockIdx.x;

  if (blk < 256) {
    const int m = blk;
    const int b = m >> 5;
    const int rem = m & 31;
    const int hc = rem >> 3;
    const int ds = rem & 7;
    const int h0 = hc * 128;
    const int d04 = ds * 16;

    const float4* Wk4 = (const float4*)Wk;
    const float4* C4b = (const float4*)(C + (size_t)b * Hn * Hn);
    #pragma unroll
    for (int p = 0; p < 8; ++p) {
      const int e = p * 256 + t;
      const int r = e >> 5, c4 = e & 31;
      *(float4*)&WkS[r][c4 * 4] = Wk4[(size_t)r * 128 + (h0 >> 2) + c4];
    }
    #pragma unroll
    for (int p = 0; p < 8; ++p) {
      const int e = p * 256 + t;
      const int r = e >> 4, c4 = e & 15;
      *(float4*)&Cs[r][c4 * 4] = C4b[(size_t)(h0 + r) * 128 + d04 + c4];
    }
    if (t < 32) *(float4*)&bks[t * 4] = ((const float4*)&bk[h0])[t];
    __syncthreads();

    const int ig = t >> 4;
    const int i4 = ig * 4;
    const int d4 = t & 15;
    float4 acc0 = make_float4(0.f, 0.f, 0.f, 0.f);
    float4 acc1 = make_float4(0.f, 0.f, 0.f, 0.f);
    float4 acc2 = make_float4(0.f, 0.f, 0.f, 0.f);
    float4 acc3 = make_float4(0.f, 0.f, 0.f, 0.f);
    float4 c1a  = make_float4(0.f, 0.f, 0.f, 0.f);

    #pragma unroll 4
    for (int h4 = 0; h4 < 128; h4 += 4) {
      const float4 w0 = *(const float4*)&WkS[i4 + 0][h4];
      const float4 w1 = *(const float4*)&WkS[i4 + 1][h4];
      const float4 w2 = *(const float4*)&WkS[i4 + 2][h4];
      const float4 w3 = *(const float4*)&WkS[i4 + 3][h4];
      const float4 c0 = *(const float4*)&Cs[h4 + 0][d4 * 4];
      const float4 c1 = *(const float4*)&Cs[h4 + 1][d4 * 4];
      const float4 c2 = *(const float4*)&Cs[h4 + 2][d4 * 4];
      const float4 c3 = *(const float4*)&Cs[h4 + 3][d4 * 4];

      acc0.x += w0.x*c0.x + w0.y*c1.x + w0.z*c2.x + w0.w*c3.x;
      acc0.y += w0.x*c0.y + w0.y*c1.y + w0.z*c2.y + w0.w*c3.y;
      acc0.z += w0.x*c0.z + w0.y*c1.z + w0.z*c2.z + w0.w*c3.z;
      acc0.w += w0.x*c0.w + w0.y*c1.w + w0.z*c2.w + w0.w*c3.w;
      acc1.x += w1.x*c0.x + w1.y*c1.x + w1.z*c2.x + w1.w*c3.x;
      acc1.y += w1.x*c0.y + w1.y*c1.y + w1.z*c2.y + w1.w*c3.y;
      acc1.z += w1.x*c0.z + w1.y*c1.z + w1.z*c2.z + w1.w*c3.z;
      acc1.w += w1.x*c0.w + w1.y*c1.w + w1.z*c2.w + w1.w*c3.w;
      acc2.x += w2.x*c0.x + w2.y*c1.x + w2.z*c2.x + w2.w*c3.x;
      acc2.y += w2.x*c0.y + w2.y*c1.y + w2.z*c2.y + w2.w*c3.y;
      acc2.z += w2.x*c0.z + w2.y*c1.z + w2.z*c2.z + w2.w*c3.z;
      acc2.w += w2.x*c0.w + w2.y*c1.w + w2.z*c2.w + w2.w*c3.w;
      acc3.x += w3.x*c0.x + w3.y*c1.x + w3.z*c2.x + w3.w*c3.x;
      acc3.y += w3.x*c0.y + w3.y*c1.y + w3.z*c2.y + w3.w*c3.y;
      acc3.z += w3.x*c0.z + w3.y*c1.z + w3.z*c2.z + w3.w*c3.z;
      acc3.w += w3.x*c0.w + w3.y*c1.w + w3.z*c2.w + w3.w*c3.w;

      if (ig == 0) {
        const float b0 = bks[h4 + 0], b1 = bks[h4 + 1];
        const float b2 = bks[h4 + 2], b3 = bks[h4 + 3];
        c1a.x += b0*c0.x + b1*c1.x + b2*c2.x + b3*c3.x;
        c1a.y += b0*c0.y + b1*c1.y + b2*c2.y + b3*c3.y;
        c1a.z += b0*c0.z + b1*c1.z + b2*c2.z + b3*c3.z;
        c1a.w += b0*c0.w + b1*c1.w + b2*c2.w + b3*c3.w;
      }
    }

    float4* MP4 = (float4*)(ws + OFF_MP);
    const size_t base = (size_t)(b * NHC + hc) * 64;
    MP4[(base + i4 + 0) * 128 + d04 + d4] = acc0;
    MP4[(base + i4 + 1) * 128 + d04 + d4] = acc1;
    MP4[(base + i4 + 2) * 128 + d04 + d4] = acc2;
    MP4[(base + i4 + 3) * 128 + d04 + d4] = acc3;
    if (ig == 0) {
      float4* c14 = (float4*)(ws + OFF_C1P);
      c14[(size_t)(b * NHC + hc) * 128 + d04 + d4] = c1a;
    }
    return;
  }

  // ---- k1b: reduce 64 STATS partials per batch (A1/A2 bf16, u/sig fp32) ----
  const int rblk = blk - 256;
  const int b = rblk >> 5, sel = (rblk >> 4) & 1, q = rblk & 15;
  const short* SBs = (const short*)(ws + OFF_STATS + (size_t)b * 64 * PS + (sel ? 2048 : 0));
  float* dst = ws + (sel ? OFF_A2R : OFF_A1R) + (size_t)b * 4096;
  const int e = q * 256 + t;
  float s = 0.f;
  #pragma unroll 8
  for (int p = 0; p < 64; ++p) s += frombf(SBs[(size_t)p * (PS * 2) + e]);
  dst[e] = s;
  if (sel == 0 && q == 0) {
    const float* UB = ws + OFF_STATS + (size_t)b * 64 * PS;
    if (t < 64) {
      float s2 = 0.f;
      #pragma unroll 8
      for (int p = 0; p < 64; ++p) s2 += UB[(size_t)p * PS + 4096 + t];
      ws[OFF_U1R + b * 64 + t] = s2;
    } else if (t < 128) {
      const int i = t - 64;
      float s2 = 0.f;
      #pragma unroll 8
      for (int p = 0; p < 64; ++p) s2 += UB[(size_t)p * PS + 4160 + i];
      ws[OFF_U2R + b * 64 + i] = s2;
    } else if (t == 128) {
      float s1 = 0.f, s2 = 0.f;
      for (int p = 0; p < 64; ++p) {
        s1 += UB[(size_t)p * PS + 4224];
        s2 += UB[(size_t)p * PS + 4225];
      }
      ws[OFF_SIG + b * 2] = s1;
      ws[OFF_SIG + b * 2 + 1] = s2;
    }
  }
}

// ---------------------------------------------------------------------------
// k2p: Td = A1 @ Wv - A2 @ M  (M = sum of 4 h-partials)
//      p1 = Wk^T u1, p2 = Wk^T u2, q1 = Wv^T u1, g = u2^T M
// grid 128 (= b(8) x ds(16, 32-wide)) x 256
__global__ __launch_bounds__(256) void k2p_td(const float* __restrict__ Wk,
                                              const float* __restrict__ Wv,
                                              float* __restrict__ ws) {
  __shared__ __align__(16) float A1s[64][66];
  __shared__ __align__(16) float A2s[64][66];
  __shared__ __align__(16) float Wvt[64][36];
  __shared__ __align__(16) float Mt[64][36];
  __shared__ __align__(16) float u1s[64];
  __shared__ __align__(16) float u2s[64];

  const int t = threadIdx.x;
  const int blk = blockIdx.x;
  const int b = blk >> 4;
  const int ds = blk & 15;
  const int d04 = ds * 8;

  const float4* A1R4 = (const float4*)(ws + OFF_A1R + (size_t)b * 4096);
  const float4* A2R4 = (const float4*)(ws + OFF_A2R + (size_t)b * 4096);
  #pragma unroll
  for (int p = 0; p < 4; ++p) {
    const int idx = p * 256 + t;
    const int r = idx >> 4, c0 = (idx & 15) * 4;
    *(float4*)&A1s[r][c0] = A1R4[idx];
    *(float4*)&A2s[r][c0] = A2R4[idx];
  }
  const float4* Wv4 = (const float4*)Wv;
  const float4* MP4 = (const float4*)(ws + OFF_MP);
  #pragma unroll
  for (int p = 0; p < 2; ++p) {
    const int idx = p * 256 + t;
    const int r = idx >> 3, c4 = idx & 7;
    *(float4*)&Wvt[r][c4 * 4] = Wv4[(size_t)r * 128 + d04 + c4];
    float4 m = MP4[((size_t)(b * NHC + 0) * 64 + r) * 128 + d04 + c4];
    #pragma unroll
    for (int q = 1; q < NHC; ++q) {
      const float4 mq = MP4[((size_t)(b * NHC + q) * 64 + r) * 128 + d04 + c4];
      m.x += mq.x; m.y += mq.y; m.z += mq.z; m.w += mq.w;
    }
    *(float4*)&Mt[r][c4 * 4] = m;
  }
  if (t < 16) {
    *(float4*)&u1s[t * 4] = *(const float4*)(ws + OFF_U1R + b * 64 + t * 4);
  } else if (t < 32) {
    const int i = t - 16;
    *(float4*)&u2s[i * 4] = *(const float4*)(ws + OFF_U2R + b * 64 + i * 4);
  }
  __syncthreads();

  const int ig = t >> 3;
  const int tj4 = t & 7;
  float4 acc0 = make_float4(0.f, 0.f, 0.f, 0.f);
  float4 acc1 = make_float4(0.f, 0.f, 0.f, 0.f);
  #pragma unroll 8
  for (int j = 0; j < 64; ++j) {
    const float4 wv = *(const float4*)&Wvt[j][tj4 * 4];
    const float4 mv = *(const float4*)&Mt[j][tj4 * 4];
    const float a10 = A1s[ig * 2][j], a20 = A2s[ig * 2][j];
    const float a11 = A1s[ig * 2 + 1][j], a21 = A2s[ig * 2 + 1][j];
    acc0.x += a10 * wv.x - a20 * mv.x; acc0.y += a10 * wv.y - a20 * mv.y;
    acc0.z += a10 * wv.z - a20 * mv.z; acc0.w += a10 * wv.w - a20 * mv.w;
    acc1.x += a11 * wv.x - a21 * mv.x; acc1.y += a11 * wv.y - a21 * mv.y;
    acc1.z += a11 * wv.z - a21 * mv.z; acc1.w += a11 * wv.w - a21 * mv.w;
  }
  float4* Td4 = (float4*)(ws + OFF_TD + (size_t)b * 64 * Hn);
  Td4[(size_t)(ig * 2)     * 128 + d04 + tj4] = acc0;
  Td4[(size_t)(ig * 2 + 1) * 128 + d04 + tj4] = acc1;

  if (t < 32) {
    const int d = ds * 32 + t;
    float q1 = 0.f, g = 0.f;
    #pragma unroll 8
    for (int i = 0; i < 64; ++i) {
      q1 += u1s[i] * Wvt[i][t];
      g  += u2s[i] * Mt[i][t];
    }
    ws[OFF_Q1 + (size_t)b * Hn + d] = q1;
    ws[OFF_GV + (size_t)b * Hn + d] = g;
  } else if (t < 64) {
    const int h = ds * 32 + (t - 32);
    float p1 = 0.f, p2 = 0.f;
    #pragma unroll 8
    for (int i = 0; i < 64; ++i) {
      const float wv = Wk[(size_t)i * Hn + h];
      p1 += wv * u1s[i];
      p2 += wv * u2s[i];
    }
    ws[OFF_P1 + (size_t)b * Hn + h] = p1;
    ws[OFF_P2 + (size_t)b * Hn + h] = p2;
  }
}

// ---------------------------------------------------------------------------
// k4: out = C + Wk^T Td + (p1 + sig1*bk) (x) bv + bk (x) (q1 - g - sig2*c1) - p2 (x) c1
// grid 512 (= b(8) x hstrip(8, 64-wide) x dstrip(8, 64-wide)) x 256
__global__ __launch_bounds__(256) void k4_out(const float* __restrict__ C,
                                              const float* __restrict__ Wk,
                                              const float* __restrict__ bk,
                                              const float* __restrict__ bv,
                                              const float* __restrict__ ws,
                                              float* __restrict__ out) {
  __shared__ __align__(16) float Tds[64][68];
  __shared__ __align__(16) float Wks[64][68];
  __shared__ float phs[64], bks[64], p2s[64];
  __shared__ float bvs[64], terms[64], c1s[64];

  const int t = threadIdx.x;
  const int blk = blockIdx.x;
  const int b = blk >> 6;
  const int rem = blk & 63;
  const int hs0 = (rem >> 3) * 64;
  const int d04 = (rem & 7) * 16;
  const float sg1 = ws[OFF_SIG + b * 2];
  const float sg2 = ws[OFF_SIG + b * 2 + 1];

  const float4* TdG4 = (const float4*)(ws + OFF_TD + (size_t)b * 64 * Hn);
  const float4* Wk4 = (const float4*)Wk;
  #pragma unroll
  for (int p = 0; p < 4; ++p) {
    const int e = p * 256 + t;
    const int r = e >> 4, c4 = e & 15;
    *(float4*)&Tds[r][c4 * 4] = TdG4[(size_t)r * 128 + d04 + c4];
    *(float4*)&Wks[r][c4 * 4] = Wk4[(size_t)r * 128 + (hs0 >> 2) + c4];
  }
  if (t < 64) {
    const int h = hs0 + t;
    const float bkv = bk[h];
    bks[t] = bkv;
    phs[t] = ws[OFF_P1 + (size_t)b * Hn + h] + sg1 * bkv;
    p2s[t] = ws[OFF_P2 + (size_t)b * Hn + h];
  } else if (t < 128) {
    const int dd = t - 64;
    const int d = d04 * 4 + dd;
    float c1 = 0.f;
    #pragma unroll
    for (int q = 0; q < NHC; ++q)
      c1 += ws[OFF_C1P + (size_t)(b * NHC + q) * Hn + d];
    c1s[dd] = c1;
    bvs[dd] = bv[d];
    terms[dd] = ws[OFF_Q1 + (size_t)b * Hn + d] - ws[OFF_GV + (size_t)b * Hn + d] - sg2 * c1;
  }
  __syncthreads();

  const int ti = t >> 4;
  const int tj4 = t & 15;
  float4 acc[4];
  #pragma unroll
  for (int a = 0; a < 4; ++a) acc[a] = make_float4(0.f, 0.f, 0.f, 0.f);
  for (int j = 0; j < 64; ++j) {
    const float4 td4 = *(const float4*)&Tds[j][tj4 * 4];
    #pragma unroll
    for (int a = 0; a < 4; ++a) {
      const float wv = Wks[j][ti * 4 + a];
      acc[a].x += wv * td4.x; acc[a].y += wv * td4.y;
      acc[a].z += wv * td4.z; acc[a].w += wv * td4.w;
    }
  }

  const float4* C4b = (const float4*)(C + (size_t)b * Hn * Hn);
  float4* out4 = (float4*)(out + (size_t)b * Hn * Hn);
  const float4 bv4 = *(const float4*)&bvs[tj4 * 4];
  const float4 tm4 = *(const float4*)&terms[tj4 * 4];
  const float4 c14 = *(const float4*)&c1s[tj4 * 4];
  #pragma unroll
  for (int a = 0; a < 4; ++a) {
    const int hh = ti * 4 + a;
    const int h = hs0 + hh;
    const float4 c = C4b[(size_t)h * 128 + d04 + tj4];
    const float ph = phs[hh], bkh = bks[hh], p2h = p2s[hh];
    float4 o;
    o.x = c.x + acc[a].x + ph * bv4.x + bkh * tm4.x - p2h * c14.x;
    o.y = c.y + acc[a].y + ph * bv4.y + bkh * tm4.y - p2h * c14.y;
    o.z = c.z + acc[a].z + ph * bv4.z + bkh * tm4.z - p2h * c14.z;
    o.w = c.w + acc[a].w + ph * bv4.w + bkh * tm4.w - p2h * c14.w;
    out4[(size_t)h * 128 + d04 + tj4] = o;
  }
}

// ---------------------------------------------------------------------------
extern "C" void kernel_launch(void* const* d_in, const int* in_sizes, int n_in,
                              void* d_out, int out_size, void* d_ws, size_t ws_size,
                              hipStream_t stream) {
  const float* hs = (const float*)d_in[0];
  const float* C  = (const float*)d_in[1];
  const float* Wk = (const float*)d_in[2];
  const float* bk = (const float*)d_in[3];
  const float* Wv = (const float*)d_in[4];
  const float* bv = (const float*)d_in[5];
  float* out = (float*)d_out;
  float* ws = (float*)d_ws;
  (void)in_sizes; (void)n_in; (void)out_size; (void)ws_size;

  hipLaunchKernelGGL(kG_pre,   dim3(65),  dim3(256), 0, stream, Wk, bk, ws);
  hipLaunchKernelGGL(k1_stats, dim3(512), dim3(256), 0, stream, hs, ws);
  hipLaunchKernelGGL(k1bM,     dim3(512), dim3(256), 0, stream, Wk, bk, C, ws);
  hipLaunchKernelGGL(k2p_td,   dim3(128), dim3(256), 0, stream, Wk, Wv, ws);
  hipLaunchKernelGGL(k4_out,   dim3(512), dim3(256), 0, stream, C, Wk, bk, bv, ws, out);
}